// Round 11
// baseline (190.389 us; speedup 1.0000x reference)
//
#include <hip/hip_runtime.h>

// ONN conv2d: B=16, Cin=128, H=W=32, Cout=256, k=3 (pad=1, stride=1)
// N=16384 positions, D=1152=18*64 chunks of VEC=64, M=256.
// out[n,m] = sum_r sign01( dot_c( x[n,64r+c], wq[64r+c,m] ) )
// wq = clamp(rintf(w*scale), -7, 7), scale = fl32(15/(fl32(max-min)+1e-9f))
//
// Main path: bf16 MFMA with x split hi/lo (w int4 exact in bf16).
// |mfma_dot - ref_fp32_chain| < ~2e-3; dots with |s| < TAU=0.03 recomputed
// bit-exactly (sequential fp32, ascending c, separate mul/add -- R4 body).
// R3..R18 ledger: best k_main = R12 (52.7us; 512thr = 4nt x 2kz in-block
// split-K, LDS merge, gather-B depth-1 prefetch, at-use A). All k_main
// micro-levers exhausted: reg A-ring (R15), LDS-DMA A (R16), occupancy
// (R13/R14/R17), global atomics (R9), i8 pivot (R18: 57.2, FETCH x3).
// R5 lesson: fix body sacred. R13: never launch_bounds past proven alloc.
// LAUNCH-OVERHEAD FINDING (R19): e2e - k_main ~= 66-70us for 3 launches,
//   91 for R18's 4 launches; prep kernels move only ~18MB (~3us of work).
//   Per-launch overhead ~= 22us dominates. Lever: 3 launches -> 2.
// R19: merge k_prep+k_quantb. min/max is ORDER-INDEPENDENT (exact same
//   bits for any reduction order; weights have no NaN/Inf, and a +-0 min
//   cannot change max-min) -> each quantb block self-computes the global
//   min/max (1.18MB float4 scan, L2-resident) and derives the SAME scale
//   bitwise as the old 64-partial path; one copy published for k_main.
//   k_main = R12 body + R15 XCD swizzle, block_scale replaced by a
//   scalar read. Fix tail / hit queue / merge verbatim.

#define TAU 0.03f
#define HITCAP 2048

typedef short short8 __attribute__((ext_vector_type(8)));
typedef float f32x4 __attribute__((ext_vector_type(4)));
typedef unsigned int uv4 __attribute__((ext_vector_type(4)));

__device__ __forceinline__ unsigned short bf16rn(float v) {
    unsigned u = __float_as_uint(v);
    unsigned r = u + 0x7fffu + ((u >> 16) & 1u);
    return (unsigned short)(r >> 16);
}

// ---------------- merged prep: xpk packing (blocks 0..2047) +
//   self-sufficient quantb (blocks 2048..2191) ----------------
// quantb block: exact global min/max via own scan (order-independent =>
// bitwise-identical scale), quantize 256 A-fragment slots, publish scale.
__global__ __launch_bounds__(256) void k_prep(const float* __restrict__ w,
                                              const float* __restrict__ inp,
                                              unsigned* __restrict__ xpk,
                                              uv4* __restrict__ wqb,
                                              float* __restrict__ wsscale) {
    const int t = threadIdx.x;
    if (blockIdx.x < 2048) {
        int bc = blockIdx.x;                   // b*128 + cin
        const float* src = inp + (size_t)bc * 1024;
        unsigned* dst = xpk + (size_t)bc * 1156;
        #pragma unroll
        for (int i = 0; i < 5; ++i) {
            int idx = t + i * 256;
            if (idx < 1156) {
                int yy = idx / 34, xx = idx - yy * 34;
                float v = 0.0f;
                int ys = yy - 1, xs_ = xx - 1;
                if ((unsigned)ys < 32u && (unsigned)xs_ < 32u) v = src[ys * 32 + xs_];
                unsigned short h = bf16rn(v);
                float hf = __uint_as_float((unsigned)h << 16);
                unsigned short l = bf16rn(v - hf);
                dst[idx] = (unsigned)h | ((unsigned)l << 16);
            }
        }
    } else {
        // ---- exact global min/max (294912 floats = 73728 float4; 288/thread) ----
        const float4* w4 = (const float4*)w;
        float vmin = 1e30f, vmax = -1e30f;
        for (int i = t; i < 73728; i += 256) {
            float4 v = w4[i];
            vmin = fminf(vmin, fminf(fminf(v.x, v.y), fminf(v.z, v.w)));
            vmax = fmaxf(vmax, fmaxf(fmaxf(v.x, v.y), fmaxf(v.z, v.w)));
        }
        #pragma unroll
        for (int off = 32; off > 0; off >>= 1) {
            vmin = fminf(vmin, __shfl_down(vmin, off, 64));
            vmax = fmaxf(vmax, __shfl_down(vmax, off, 64));
        }
        __shared__ float smin[4], smax[4];
        __shared__ float sca;
        int wave = t >> 6;
        if ((t & 63) == 0) { smin[wave] = vmin; smax[wave] = vmax; }
        __syncthreads();
        if (t == 0) {
            #pragma unroll
            for (int i = 1; i < 4; i++) {
                vmin = fminf(vmin, smin[i]);
                vmax = fmaxf(vmax, smax[i]);
            }
            float tt = __fadd_rn(__fsub_rn(vmax, vmin), 1e-9f);   // SAME expr as ever
            sca = __fdiv_rn(15.0f, tt);
            wsscale[0] = sca;               // all quantb blocks write identical bits
        }
        __syncthreads();
        float s = sca;

        // ---- quantb body (verbatim math): slot = qb*256 + t ----
        // slot = ((g*18 + r)*8 + mt*2 + khalf)*64 + lane ; 16B per slot
        // value(lane,j) = wq[d=64r+khalf*32+(lane>>4)*8+j][m=g*64+mt*16+(lane&15)]
        int slot = (int)(blockIdx.x - 2048) * 256 + t;   // 0..36863
        int lane = slot & 63;
        int sub = slot >> 6;
        int khalf = sub & 1;
        int mt = (sub >> 1) & 3;
        int gr = sub >> 3;                 // g*18 + r
        int g = gr / 18, r = gr - g * 18;
        int m = g * 64 + mt * 16 + (lane & 15);
        int dbase = r * 64 + khalf * 32 + (lane >> 4) * 8;
        const float* wp = w + (size_t)m * 1152 + dbase;
        unsigned o[4];
        #pragma unroll
        for (int p = 0; p < 4; ++p) {
            float q0 = rintf(__fmul_rn(wp[2 * p], s));
            float q1 = rintf(__fmul_rn(wp[2 * p + 1], s));
            q0 = fminf(fmaxf(q0, -7.0f), 7.0f);
            q1 = fminf(fmaxf(q1, -7.0f), 7.0f);
            o[p] = (unsigned)bf16rn(q0) | ((unsigned)bf16rn(q1) << 16);
        }
        uv4 v; v.x = o[0]; v.y = o[1]; v.z = o[2]; v.w = o[3];
        wqb[slot] = v;
    }
}

// gather: uniform SGPR base + per-lane 32-bit byte offset (xdelta + plane ofs)
#define XLD(o) (*reinterpret_cast<const unsigned*>(xpkB + (xdelta + (unsigned)(o))))

// issue the 16 B-gather u32 loads for chunk rr into dst[16]
// (byte offsets via 4x ds_read_b128; q2<8 -> khalf0, q2>=8 -> khalf1)
#define ISSUE_B(rr, dst) do {                                                  \
    const int4* _oa = reinterpret_cast<const int4*>(&ofs_s[(rr) * 64 + quad * 8]); \
    int4 _o0 = _oa[0], _o1 = _oa[1];                                           \
    const int4* _ob = reinterpret_cast<const int4*>(&ofs_s[(rr) * 64 + 32 + quad * 8]); \
    int4 _o2 = _ob[0], _o3 = _ob[1];                                           \
    dst[0] = XLD(_o0.x); dst[1] = XLD(_o0.y); dst[2] = XLD(_o0.z); dst[3] = XLD(_o0.w); \
    dst[4] = XLD(_o1.x); dst[5] = XLD(_o1.y); dst[6] = XLD(_o1.z); dst[7] = XLD(_o1.w); \
    dst[8] = XLD(_o2.x); dst[9] = XLD(_o2.y); dst[10] = XLD(_o2.z); dst[11] = XLD(_o2.w); \
    dst[12] = XLD(_o3.x); dst[13] = XLD(_o3.y); dst[14] = XLD(_o3.z); dst[15] = XLD(_o3.w); \
} while (0)

// A-fragment slot index for (chunk rr, m-tile mm) at this lane (mm in 0..7;
// wqb layout has 4 original g-groups of 4 mt, our 128m half spans 2 groups)
#define AIDX(rr, mm) ((((mm) >> 2) * 9216) + (rr) * 512 + (((mm) & 3) * 128))

// ---------------- main: in-block split-K gather GEMM (512 thr) + fix ----------------
// 8 waves = 4 n-tiles x 2 kz halves; each wave: 16n x 128m x 9 chunks.
// kz=1 waves deposit packed negcnt in LDS; kz=0 waves merge + store.
__global__ __launch_bounds__(512, 4) void k_main(const unsigned* __restrict__ xpk,
                                                 const uv4* __restrict__ wqb,
                                                 const float* __restrict__ inp,
                                                 const float* __restrict__ weight,
                                                 const float* __restrict__ wsscale,
                                                 float* __restrict__ out) {
    __shared__ alignas(16) int ofs_s[1152]; // BYTE plane offset per k: (cin*1156+kh*34+kw)*4
    __shared__ unsigned hitbuf[HITCAP];
    __shared__ unsigned red_s[4][64][9];    // [nt][lane][mt] packed bytes (+pad col)
    __shared__ unsigned hitcnt;

    const int t = threadIdx.x;
    if (t == 0) hitcnt = 0u;
    const float sc = wsscale[0];            // bitwise == prep's scale
    for (int k = t; k < 1152; k += 512) {
        int cin = k / 9;
        int rem = k - cin * 9;
        int kh = rem / 3;
        int kw = rem - kh * 3;
        ofs_s[k] = (cin * 1156 + kh * 34 + kw) * 4;
    }
    __syncthreads();                        // covers hitcnt init + ofs_s

    // XCD-bijective swizzle (R15-proven): 512 blocks, 64 consecutive per XCD;
    // each XCD shares one g-half (wqb 295KB L2-resident) + contiguous n.
    const int lin = (int)(blockIdx.y * gridDim.x + blockIdx.x);   // 0..511
    const int nlin = (lin & 7) * 64 + (lin >> 3);
    const int g = nlin >> 8;           // 128-m half: m in [g*128, g*128+128)
    const int n0 = (nlin & 255) * 64;

    const int lane = t & 63;
    const int wv8 = t >> 6;            // 0..7
    const int nt = wv8 >> 1;           // n-tile 0..3
    const int kz = wv8 & 1;            // K half: chunks [kz*9, kz*9+9)
    const int quad = lane >> 4;
    const int nl = lane & 15;
    const int b = n0 >> 10;
    const int r0 = kz * 9, rend = r0 + 9;

    // wave's image-position base (16 consecutive positions within one row)
    const int sy_w = ((n0 & 1023) >> 5) + (nt >> 1);
    const int col0 = (nt & 1) * 16;
    const char* __restrict__ xpkB = (const char*)xpk;   // uniform base (SGPR)
    const unsigned xdelta =
        ((unsigned)b * (128u * 1156u) + (unsigned)(sy_w * 34 + col0 + nl)) * 4u;
    const uv4* __restrict__ aw = wqb + (size_t)g * (2 * 18 * 512) + lane;

    // negcnt packed: [mt][pair] u32, two 16-bit counters (i=2p lo, i=2p+1 hi)
    unsigned negpk[8][2] = {};
    unsigned long long hitacc = 0ull;

    // ---- prologue: prefetch chunk r0's B-gather u32s and (r0, mt0) A-frags ----
    unsigned pb[16];
    ISSUE_B(r0, pb);
    short8 ac0 = __builtin_bit_cast(short8, aw[AIDX(r0, 0)]);
    short8 ac1 = __builtin_bit_cast(short8, aw[AIDX(r0, 0) + 64]);

    for (int r = r0; r < rend; ++r) {
        // ---- repack current B (split packed hi|lo) via v_perm_b32 ----
        short8 bhi[2], blo[2];
        #pragma unroll
        for (int kh2 = 0; kh2 < 2; ++kh2) {
            union { unsigned d[4]; short8 v; } H, L;
            #pragma unroll
            for (int p = 0; p < 4; ++p) {
                unsigned ua = pb[kh2 * 8 + 2 * p], ub = pb[kh2 * 8 + 2 * p + 1];
                H.d[p] = __builtin_amdgcn_perm(ub, ua, 0x05040100u); // ua.lo | ub.lo<<16
                L.d[p] = __builtin_amdgcn_perm(ub, ua, 0x07060302u); // ua.hi | ub.hi<<16
            }
            bhi[kh2] = H.v;
            blo[kh2] = L.v;
        }

        // issue next chunk's gathers, branchless (last r harmlessly reloads)
        const int rn = (r + 1 < rend) ? r + 1 : r;
        ISSUE_B(rn, pb);

        // ---- 8 m-tiles, fully branchless; rolling depth-1 A-pair prefetch ----
        f32x4 accs[8];
        #pragma unroll
        for (int mt = 0; mt < 8; ++mt) {
            const int pn = (mt == 7) ? AIDX(rn, 0) : AIDX(r, mt + 1);
            short8 an0 = __builtin_bit_cast(short8, aw[pn]);
            short8 an1 = __builtin_bit_cast(short8, aw[pn + 64]);

            f32x4 acc = {0.0f, 0.0f, 0.0f, 0.0f};
            acc = __builtin_amdgcn_mfma_f32_16x16x32_bf16(ac0, bhi[0], acc, 0, 0, 0);
            acc = __builtin_amdgcn_mfma_f32_16x16x32_bf16(ac1, bhi[1], acc, 0, 0, 0);
            acc = __builtin_amdgcn_mfma_f32_16x16x32_bf16(ac0, blo[0], acc, 0, 0, 0);
            acc = __builtin_amdgcn_mfma_f32_16x16x32_bf16(ac1, blo[1], acc, 0, 0, 0);
            accs[mt] = acc;
            #pragma unroll
            for (int p = 0; p < 2; ++p) {
                unsigned sb0 = __float_as_uint(acc[2 * p]) >> 31;
                unsigned sb1 = __float_as_uint(acc[2 * p + 1]) >> 31;
                negpk[mt][p] += sb0 + (sb1 << 16);
                hitacc |= __ballot(__builtin_fabsf(acc[2 * p]) < TAU);
                hitacc |= __ballot(__builtin_fabsf(acc[2 * p + 1]) < TAU);
            }
            ac0 = an0;
            ac1 = an1;
        }

        // ---- one rare cold branch per chunk: queue hits (per-lane id rebuilt) ----
        if (hitacc) {
            #pragma unroll
            for (int mt = 0; mt < 8; ++mt)
                #pragma unroll
                for (int i = 0; i < 4; ++i) {
                    float s = accs[mt][i];
                    if (__builtin_fabsf(s) < TAU) {
                        unsigned ge = (__float_as_uint(s) >> 31) ^ 1u;   // match negpk
                        unsigned idx = atomicAdd(&hitcnt, 1u);           // LDS atomic: rare
                        if (idx < (unsigned)HITCAP) {
                            unsigned m = (unsigned)(g * 128 + mt * 16 + quad * 4 + i);
                            unsigned n = (unsigned)(n0 + nt * 16 + nl);
                            hitbuf[idx] = n | ((unsigned)r << 14) | (m << 19)
                                            | (ge << 27);
                        }
                    }
                }
            hitacc = 0ull;
        }
    }

    // ---- merge kz halves via LDS; kz=0 waves store final counts ----
    if (kz == 1) {
        #pragma unroll
        for (int mt = 0; mt < 8; ++mt) {
            unsigned c0 = negpk[mt][0] & 0xffffu, c1 = negpk[mt][0] >> 16;
            unsigned c2 = negpk[mt][1] & 0xffffu, c3 = negpk[mt][1] >> 16;
            red_s[nt][lane][mt] = c0 | (c1 << 8) | (c2 << 16) | (c3 << 24);
        }
    }
    __syncthreads();
    if (kz == 0) {
        const int n = n0 + nt * 16 + nl;
        const int p = n & 1023;
        #pragma unroll
        for (int mt = 0; mt < 8; ++mt) {
            unsigned pk = red_s[nt][lane][mt];
            unsigned tot0 = (negpk[mt][0] & 0xffffu) + (pk & 255u);
            unsigned tot1 = (negpk[mt][0] >> 16) + ((pk >> 8) & 255u);
            unsigned tot2 = (negpk[mt][1] & 0xffffu) + ((pk >> 16) & 255u);
            unsigned tot3 = (negpk[mt][1] >> 16) + (pk >> 24);
            int mb = g * 128 + mt * 16 + quad * 4;
            size_t obase = ((size_t)(b * 256 + mb)) << 10;
            out[obase + p]                = (float)(18u - tot0);
            out[obase + (1ull << 10) + p] = (float)(18u - tot1);
            out[obase + (2ull << 10) + p] = (float)(18u - tot2);
            out[obase + (3ull << 10) + p] = (float)(18u - tot3);
        }
    }

    // ---- in-block fixup of this block's own hits (R4 k_fix body, verbatim math) ----
    __syncthreads();
    unsigned tot = hitcnt;
    if (tot > (unsigned)HITCAP) tot = (unsigned)HITCAP;
    for (unsigned i = t; i < tot; i += 512) {
        unsigned u = hitbuf[i];
        int n = u & 16383;
        int r = (u >> 14) & 31;
        int m = (u >> 19) & 255;
        int bit = (u >> 27) & 1;
        int bb = n >> 10, p = n & 1023, y = p >> 5, x = p & 31;
        const float* ib = inp + (size_t)bb * (128 * 32 * 32);
        const float* wp = weight + (size_t)m * 1152;
        float s = 0.0f;
        int d = r * 64;
        for (int c = 0; c < 64; ++c, ++d) {
            int ci = d / 9, rem = d - ci * 9;
            int kh = rem / 3, kw = rem - kh * 3;
            int yy = y + kh - 1, xx = x + kw - 1;
            float xv = 0.0f;
            if ((unsigned)yy < 32u && (unsigned)xx < 32u)
                xv = ib[(ci * 32 + yy) * 32 + xx];
            float q = rintf(__fmul_rn(wp[d], sc));
            q = fminf(fmaxf(q, -7.0f), 7.0f);
            s = __fadd_rn(s, __fmul_rn(xv, q));
        }
        int nb = (s >= 0.0f) ? 1 : 0;
        if (nb != bit)
            atomicAdd(&out[(((size_t)(bb * 256 + m)) << 10) + p], nb ? 1.0f : -1.0f);
    }
}

extern "C" void kernel_launch(void* const* d_in, const int* in_sizes, int n_in,
                              void* d_out, int out_size, void* d_ws, size_t ws_size,
                              hipStream_t stream) {
    const float* inp    = (const float*)d_in[0];   // [16,128,32,32]
    const float* weight = (const float*)d_in[1];   // [256,128,3,3]
    float* out = (float*)d_out;                    // [16,256,32,32]

    char* ws = (char*)d_ws;
    float*    wsscale = (float*)(ws + 0);          // 1 float (256B slot)
    uv4*      wqb     = (uv4*)(ws + 1024);         // 589,824 B
    unsigned* xpk     = (unsigned*)(ws + 590848);  // 9,469,952 B

    // 2 launches total (was 3): merged prep (packing + self-sufficient quantb)
    k_prep<<<2192, 256, 0, stream>>>(weight, inp, xpk, wqb, wsscale);

    dim3 grid(256, 2);   // (N/64, M/128); 512-thread blocks, split-K in-block
    k_main<<<grid, 512, 0, stream>>>(xpk, wqb, inp, weight, wsscale, out);
}

// Round 12
// 136.548 us; speedup vs baseline: 1.3943x; 1.3943x over previous
//
#include <hip/hip_runtime.h>

// ONN conv2d: B=16, Cin=128, H=W=32, Cout=256, k=3 (pad=1, stride=1)
// N=16384 positions, D=1152=18*64 chunks of VEC=64, M=256.
// out[n,m] = sum_r sign01( dot_c( x[n,64r+c], wq[64r+c,m] ) )
// wq = clamp(rintf(w*scale), -7, 7), scale = fl32(15/(fl32(max-min)+1e-9f))
//
// Main path: bf16 MFMA with x split hi/lo (w int4 exact in bf16).
// |mfma_dot - ref_fp32_chain| < ~2e-3; dots with |s| < TAU=0.03 recomputed
// bit-exactly (sequential fp32, ascending c, separate mul/add -- R4 body).
// R3..R18 ledger: best k_main = R12 (52.7us; 512thr = 4nt x 2kz in-block
// split-K, LDS merge, gather-B depth-1 prefetch, at-use A). All k_main
// micro-levers exhausted (R9/R13-R18). R5: fix body sacred.
// R19: 3 launches -> 2 by merging prep+quantb (min/max order-independent
//   => each quantb block self-computes scale, bitwise identical).
//   STRUCTURE worked; the scan did NOT: rolled loop compiled to VGPR=12,
//   1-outstanding-load serial chain -> k_prep 131us (288 x ~300-900cyc
//   load-wait). Classic MLP failure, visible as VALUBusy 3.6%/Occ 9%.
// R20: unroll the scan 8x with 8 INDEPENDENT min/max accumulators
//   (36 iters x 8 loads in flight; coverage t+u*256+iter*2048 bijective
//   over 73728 float4). Same multiset, any order => bitwise-same scale.
//   Everything else R19-verbatim.

#define TAU 0.03f
#define HITCAP 2048

typedef short short8 __attribute__((ext_vector_type(8)));
typedef float f32x4 __attribute__((ext_vector_type(4)));
typedef unsigned int uv4 __attribute__((ext_vector_type(4)));

__device__ __forceinline__ unsigned short bf16rn(float v) {
    unsigned u = __float_as_uint(v);
    unsigned r = u + 0x7fffu + ((u >> 16) & 1u);
    return (unsigned short)(r >> 16);
}

// ---------------- merged prep: xpk packing (blocks 0..2047) +
//   self-sufficient quantb (blocks 2048..2191) ----------------
// quantb block: exact global min/max via 8-way-MLP scan (order-independent
// => bitwise-identical scale), quantize 256 A-fragment slots, publish scale.
__global__ __launch_bounds__(256) void k_prep(const float* __restrict__ w,
                                              const float* __restrict__ inp,
                                              unsigned* __restrict__ xpk,
                                              uv4* __restrict__ wqb,
                                              float* __restrict__ wsscale) {
    const int t = threadIdx.x;
    if (blockIdx.x < 2048) {
        int bc = blockIdx.x;                   // b*128 + cin
        const float* src = inp + (size_t)bc * 1024;
        unsigned* dst = xpk + (size_t)bc * 1156;
        #pragma unroll
        for (int i = 0; i < 5; ++i) {
            int idx = t + i * 256;
            if (idx < 1156) {
                int yy = idx / 34, xx = idx - yy * 34;
                float v = 0.0f;
                int ys = yy - 1, xs_ = xx - 1;
                if ((unsigned)ys < 32u && (unsigned)xs_ < 32u) v = src[ys * 32 + xs_];
                unsigned short h = bf16rn(v);
                float hf = __uint_as_float((unsigned)h << 16);
                unsigned short l = bf16rn(v - hf);
                dst[idx] = (unsigned)h | ((unsigned)l << 16);
            }
        }
    } else {
        // ---- exact global min/max, 8 independent accumulators (MLP=8):
        //      294912 floats = 73728 float4 = 36 iters x 8 lanes x 256 thr ----
        const float4* w4 = (const float4*)w;
        float mnA[8], mxA[8];
        #pragma unroll
        for (int u = 0; u < 8; ++u) { mnA[u] = 1e30f; mxA[u] = -1e30f; }
        for (int i = t; i < 73728; i += 2048) {
            #pragma unroll
            for (int u = 0; u < 8; ++u) {
                float4 v = w4[i + u * 256];
                mnA[u] = fminf(mnA[u], fminf(fminf(v.x, v.y), fminf(v.z, v.w)));
                mxA[u] = fmaxf(mxA[u], fmaxf(fmaxf(v.x, v.y), fmaxf(v.z, v.w)));
            }
        }
        float vmin = 1e30f, vmax = -1e30f;
        #pragma unroll
        for (int u = 0; u < 8; ++u) {
            vmin = fminf(vmin, mnA[u]);
            vmax = fmaxf(vmax, mxA[u]);
        }
        #pragma unroll
        for (int off = 32; off > 0; off >>= 1) {
            vmin = fminf(vmin, __shfl_down(vmin, off, 64));
            vmax = fmaxf(vmax, __shfl_down(vmax, off, 64));
        }
        __shared__ float smin[4], smax[4];
        __shared__ float sca;
        int wave = t >> 6;
        if ((t & 63) == 0) { smin[wave] = vmin; smax[wave] = vmax; }
        __syncthreads();
        if (t == 0) {
            #pragma unroll
            for (int i = 1; i < 4; i++) {
                vmin = fminf(vmin, smin[i]);
                vmax = fmaxf(vmax, smax[i]);
            }
            float tt = __fadd_rn(__fsub_rn(vmax, vmin), 1e-9f);   // SAME expr as ever
            sca = __fdiv_rn(15.0f, tt);
            wsscale[0] = sca;               // all quantb blocks write identical bits
        }
        __syncthreads();
        float s = sca;

        // ---- quantb body (verbatim math): slot = qb*256 + t ----
        // slot = ((g*18 + r)*8 + mt*2 + khalf)*64 + lane ; 16B per slot
        // value(lane,j) = wq[d=64r+khalf*32+(lane>>4)*8+j][m=g*64+mt*16+(lane&15)]
        int slot = (int)(blockIdx.x - 2048) * 256 + t;   // 0..36863
        int lane = slot & 63;
        int sub = slot >> 6;
        int khalf = sub & 1;
        int mt = (sub >> 1) & 3;
        int gr = sub >> 3;                 // g*18 + r
        int g = gr / 18, r = gr - g * 18;
        int m = g * 64 + mt * 16 + (lane & 15);
        int dbase = r * 64 + khalf * 32 + (lane >> 4) * 8;
        const float* wp = w + (size_t)m * 1152 + dbase;
        unsigned o[4];
        #pragma unroll
        for (int p = 0; p < 4; ++p) {
            float q0 = rintf(__fmul_rn(wp[2 * p], s));
            float q1 = rintf(__fmul_rn(wp[2 * p + 1], s));
            q0 = fminf(fmaxf(q0, -7.0f), 7.0f);
            q1 = fminf(fmaxf(q1, -7.0f), 7.0f);
            o[p] = (unsigned)bf16rn(q0) | ((unsigned)bf16rn(q1) << 16);
        }
        uv4 v; v.x = o[0]; v.y = o[1]; v.z = o[2]; v.w = o[3];
        wqb[slot] = v;
    }
}

// gather: uniform SGPR base + per-lane 32-bit byte offset (xdelta + plane ofs)
#define XLD(o) (*reinterpret_cast<const unsigned*>(xpkB + (xdelta + (unsigned)(o))))

// issue the 16 B-gather u32 loads for chunk rr into dst[16]
// (byte offsets via 4x ds_read_b128; q2<8 -> khalf0, q2>=8 -> khalf1)
#define ISSUE_B(rr, dst) do {                                                  \
    const int4* _oa = reinterpret_cast<const int4*>(&ofs_s[(rr) * 64 + quad * 8]); \
    int4 _o0 = _oa[0], _o1 = _oa[1];                                           \
    const int4* _ob = reinterpret_cast<const int4*>(&ofs_s[(rr) * 64 + 32 + quad * 8]); \
    int4 _o2 = _ob[0], _o3 = _ob[1];                                           \
    dst[0] = XLD(_o0.x); dst[1] = XLD(_o0.y); dst[2] = XLD(_o0.z); dst[3] = XLD(_o0.w); \
    dst[4] = XLD(_o1.x); dst[5] = XLD(_o1.y); dst[6] = XLD(_o1.z); dst[7] = XLD(_o1.w); \
    dst[8] = XLD(_o2.x); dst[9] = XLD(_o2.y); dst[10] = XLD(_o2.z); dst[11] = XLD(_o2.w); \
    dst[12] = XLD(_o3.x); dst[13] = XLD(_o3.y); dst[14] = XLD(_o3.z); dst[15] = XLD(_o3.w); \
} while (0)

// A-fragment slot index for (chunk rr, m-tile mm) at this lane (mm in 0..7;
// wqb layout has 4 original g-groups of 4 mt, our 128m half spans 2 groups)
#define AIDX(rr, mm) ((((mm) >> 2) * 9216) + (rr) * 512 + (((mm) & 3) * 128))

// ---------------- main: in-block split-K gather GEMM (512 thr) + fix ----------------
// 8 waves = 4 n-tiles x 2 kz halves; each wave: 16n x 128m x 9 chunks.
// kz=1 waves deposit packed negcnt in LDS; kz=0 waves merge + store.
__global__ __launch_bounds__(512, 4) void k_main(const unsigned* __restrict__ xpk,
                                                 const uv4* __restrict__ wqb,
                                                 const float* __restrict__ inp,
                                                 const float* __restrict__ weight,
                                                 const float* __restrict__ wsscale,
                                                 float* __restrict__ out) {
    __shared__ alignas(16) int ofs_s[1152]; // BYTE plane offset per k: (cin*1156+kh*34+kw)*4
    __shared__ unsigned hitbuf[HITCAP];
    __shared__ unsigned red_s[4][64][9];    // [nt][lane][mt] packed bytes (+pad col)
    __shared__ unsigned hitcnt;

    const int t = threadIdx.x;
    if (t == 0) hitcnt = 0u;
    const float sc = wsscale[0];            // bitwise == prep's scale
    for (int k = t; k < 1152; k += 512) {
        int cin = k / 9;
        int rem = k - cin * 9;
        int kh = rem / 3;
        int kw = rem - kh * 3;
        ofs_s[k] = (cin * 1156 + kh * 34 + kw) * 4;
    }
    __syncthreads();                        // covers hitcnt init + ofs_s

    // XCD-bijective swizzle (R15-proven): 512 blocks, 64 consecutive per XCD;
    // each XCD shares one g-half (wqb 295KB L2-resident) + contiguous n.
    const int lin = (int)(blockIdx.y * gridDim.x + blockIdx.x);   // 0..511
    const int nlin = (lin & 7) * 64 + (lin >> 3);
    const int g = nlin >> 8;           // 128-m half: m in [g*128, g*128+128)
    const int n0 = (nlin & 255) * 64;

    const int lane = t & 63;
    const int wv8 = t >> 6;            // 0..7
    const int nt = wv8 >> 1;           // n-tile 0..3
    const int kz = wv8 & 1;            // K half: chunks [kz*9, kz*9+9)
    const int quad = lane >> 4;
    const int nl = lane & 15;
    const int b = n0 >> 10;
    const int r0 = kz * 9, rend = r0 + 9;

    // wave's image-position base (16 consecutive positions within one row)
    const int sy_w = ((n0 & 1023) >> 5) + (nt >> 1);
    const int col0 = (nt & 1) * 16;
    const char* __restrict__ xpkB = (const char*)xpk;   // uniform base (SGPR)
    const unsigned xdelta =
        ((unsigned)b * (128u * 1156u) + (unsigned)(sy_w * 34 + col0 + nl)) * 4u;
    const uv4* __restrict__ aw = wqb + (size_t)g * (2 * 18 * 512) + lane;

    // negcnt packed: [mt][pair] u32, two 16-bit counters (i=2p lo, i=2p+1 hi)
    unsigned negpk[8][2] = {};
    unsigned long long hitacc = 0ull;

    // ---- prologue: prefetch chunk r0's B-gather u32s and (r0, mt0) A-frags ----
    unsigned pb[16];
    ISSUE_B(r0, pb);
    short8 ac0 = __builtin_bit_cast(short8, aw[AIDX(r0, 0)]);
    short8 ac1 = __builtin_bit_cast(short8, aw[AIDX(r0, 0) + 64]);

    for (int r = r0; r < rend; ++r) {
        // ---- repack current B (split packed hi|lo) via v_perm_b32 ----
        short8 bhi[2], blo[2];
        #pragma unroll
        for (int kh2 = 0; kh2 < 2; ++kh2) {
            union { unsigned d[4]; short8 v; } H, L;
            #pragma unroll
            for (int p = 0; p < 4; ++p) {
                unsigned ua = pb[kh2 * 8 + 2 * p], ub = pb[kh2 * 8 + 2 * p + 1];
                H.d[p] = __builtin_amdgcn_perm(ub, ua, 0x05040100u); // ua.lo | ub.lo<<16
                L.d[p] = __builtin_amdgcn_perm(ub, ua, 0x07060302u); // ua.hi | ub.hi<<16
            }
            bhi[kh2] = H.v;
            blo[kh2] = L.v;
        }

        // issue next chunk's gathers, branchless (last r harmlessly reloads)
        const int rn = (r + 1 < rend) ? r + 1 : r;
        ISSUE_B(rn, pb);

        // ---- 8 m-tiles, fully branchless; rolling depth-1 A-pair prefetch ----
        f32x4 accs[8];
        #pragma unroll
        for (int mt = 0; mt < 8; ++mt) {
            const int pn = (mt == 7) ? AIDX(rn, 0) : AIDX(r, mt + 1);
            short8 an0 = __builtin_bit_cast(short8, aw[pn]);
            short8 an1 = __builtin_bit_cast(short8, aw[pn + 64]);

            f32x4 acc = {0.0f, 0.0f, 0.0f, 0.0f};
            acc = __builtin_amdgcn_mfma_f32_16x16x32_bf16(ac0, bhi[0], acc, 0, 0, 0);
            acc = __builtin_amdgcn_mfma_f32_16x16x32_bf16(ac1, bhi[1], acc, 0, 0, 0);
            acc = __builtin_amdgcn_mfma_f32_16x16x32_bf16(ac0, blo[0], acc, 0, 0, 0);
            acc = __builtin_amdgcn_mfma_f32_16x16x32_bf16(ac1, blo[1], acc, 0, 0, 0);
            accs[mt] = acc;
            #pragma unroll
            for (int p = 0; p < 2; ++p) {
                unsigned sb0 = __float_as_uint(acc[2 * p]) >> 31;
                unsigned sb1 = __float_as_uint(acc[2 * p + 1]) >> 31;
                negpk[mt][p] += sb0 + (sb1 << 16);
                hitacc |= __ballot(__builtin_fabsf(acc[2 * p]) < TAU);
                hitacc |= __ballot(__builtin_fabsf(acc[2 * p + 1]) < TAU);
            }
            ac0 = an0;
            ac1 = an1;
        }

        // ---- one rare cold branch per chunk: queue hits (per-lane id rebuilt) ----
        if (hitacc) {
            #pragma unroll
            for (int mt = 0; mt < 8; ++mt)
                #pragma unroll
                for (int i = 0; i < 4; ++i) {
                    float s = accs[mt][i];
                    if (__builtin_fabsf(s) < TAU) {
                        unsigned ge = (__float_as_uint(s) >> 31) ^ 1u;   // match negpk
                        unsigned idx = atomicAdd(&hitcnt, 1u);           // LDS atomic: rare
                        if (idx < (unsigned)HITCAP) {
                            unsigned m = (unsigned)(g * 128 + mt * 16 + quad * 4 + i);
                            unsigned n = (unsigned)(n0 + nt * 16 + nl);
                            hitbuf[idx] = n | ((unsigned)r << 14) | (m << 19)
                                            | (ge << 27);
                        }
                    }
                }
            hitacc = 0ull;
        }
    }

    // ---- merge kz halves via LDS; kz=0 waves store final counts ----
    if (kz == 1) {
        #pragma unroll
        for (int mt = 0; mt < 8; ++mt) {
            unsigned c0 = negpk[mt][0] & 0xffffu, c1 = negpk[mt][0] >> 16;
            unsigned c2 = negpk[mt][1] & 0xffffu, c3 = negpk[mt][1] >> 16;
            red_s[nt][lane][mt] = c0 | (c1 << 8) | (c2 << 16) | (c3 << 24);
        }
    }
    __syncthreads();
    if (kz == 0) {
        const int n = n0 + nt * 16 + nl;
        const int p = n & 1023;
        #pragma unroll
        for (int mt = 0; mt < 8; ++mt) {
            unsigned pk = red_s[nt][lane][mt];
            unsigned tot0 = (negpk[mt][0] & 0xffffu) + (pk & 255u);
            unsigned tot1 = (negpk[mt][0] >> 16) + ((pk >> 8) & 255u);
            unsigned tot2 = (negpk[mt][1] & 0xffffu) + ((pk >> 16) & 255u);
            unsigned tot3 = (negpk[mt][1] >> 16) + (pk >> 24);
            int mb = g * 128 + mt * 16 + quad * 4;
            size_t obase = ((size_t)(b * 256 + mb)) << 10;
            out[obase + p]                = (float)(18u - tot0);
            out[obase + (1ull << 10) + p] = (float)(18u - tot1);
            out[obase + (2ull << 10) + p] = (float)(18u - tot2);
            out[obase + (3ull << 10) + p] = (float)(18u - tot3);
        }
    }

    // ---- in-block fixup of this block's own hits (R4 k_fix body, verbatim math) ----
    __syncthreads();
    unsigned tot = hitcnt;
    if (tot > (unsigned)HITCAP) tot = (unsigned)HITCAP;
    for (unsigned i = t; i < tot; i += 512) {
        unsigned u = hitbuf[i];
        int n = u & 16383;
        int r = (u >> 14) & 31;
        int m = (u >> 19) & 255;
        int bit = (u >> 27) & 1;
        int bb = n >> 10, p = n & 1023, y = p >> 5, x = p & 31;
        const float* ib = inp + (size_t)bb * (128 * 32 * 32);
        const float* wp = weight + (size_t)m * 1152;
        float s = 0.0f;
        int d = r * 64;
        for (int c = 0; c < 64; ++c, ++d) {
            int ci = d / 9, rem = d - ci * 9;
            int kh = rem / 3, kw = rem - kh * 3;
            int yy = y + kh - 1, xx = x + kw - 1;
            float xv = 0.0f;
            if ((unsigned)yy < 32u && (unsigned)xx < 32u)
                xv = ib[(ci * 32 + yy) * 32 + xx];
            float q = rintf(__fmul_rn(wp[d], sc));
            q = fminf(fmaxf(q, -7.0f), 7.0f);
            s = __fadd_rn(s, __fmul_rn(xv, q));
        }
        int nb = (s >= 0.0f) ? 1 : 0;
        if (nb != bit)
            atomicAdd(&out[(((size_t)(bb * 256 + m)) << 10) + p], nb ? 1.0f : -1.0f);
    }
}

extern "C" void kernel_launch(void* const* d_in, const int* in_sizes, int n_in,
                              void* d_out, int out_size, void* d_ws, size_t ws_size,
                              hipStream_t stream) {
    const float* inp    = (const float*)d_in[0];   // [16,128,32,32]
    const float* weight = (const float*)d_in[1];   // [256,128,3,3]
    float* out = (float*)d_out;                    // [16,256,32,32]

    char* ws = (char*)d_ws;
    float*    wsscale = (float*)(ws + 0);          // 1 float (256B slot)
    uv4*      wqb     = (uv4*)(ws + 1024);         // 589,824 B
    unsigned* xpk     = (unsigned*)(ws + 590848);  // 9,469,952 B

    // 2 launches total: merged prep (packing + self-sufficient quantb)
    k_prep<<<2192, 256, 0, stream>>>(weight, inp, xpk, wqb, wsscale);

    dim3 grid(256, 2);   // (N/64, M/128); 512-thread blocks, split-K in-block
    k_main<<<grid, 512, 0, stream>>>(xpk, wqb, inp, weight, wsscale, out);
}